// Round 1
// baseline (249.371 us; speedup 1.0000x reference)
//
#include <hip/hip_runtime.h>

typedef float f32x4 __attribute__((ext_vector_type(4)));
typedef _Float16 f16x4 __attribute__((ext_vector_type(4)));

#define MFMA_F16 __builtin_amdgcn_mfma_f32_16x16x16f16

namespace {
constexpr float DT = 0.05f;
constexpr int NSTEPS = 4;
constexpr int TM = 8;  // Taylor order for exp(D*S); ||D*S|| <~ 0.4 -> err < 1e-9

struct Split { f16x4 h; f16x4 l; };

// fp32 -> (hi,lo) f16 split, elementwise (lane-local). hi+lo represents x to ~2^-22 rel.
__device__ __forceinline__ Split mksplit(f32x4 v) {
  Split s;
#pragma unroll
  for (int i = 0; i < 4; ++i) {
    float x = v[i];
    _Float16 hi = (_Float16)x;
    s.h[i] = hi;
    s.l[i] = (_Float16)(x - (float)hi);
  }
  return s;
}

// C = A * B via 3-term split product (drop lo*lo).
// Register layout for all matrices: C/D layout of 16x16 MFMA:
//   lane holds rows 4*(lane>>4)+i (i=0..3) at col (lane&15).
// This equals the B-fragment layout always, and the A-fragment layout when the
// matrix is symmetric. So: A must be (numerically) symmetric; B arbitrary.
__device__ __forceinline__ f32x4 mm(Split a, Split b) {
  f32x4 acc = {0.f, 0.f, 0.f, 0.f};
  acc = MFMA_F16(a.h, b.h, acc, 0, 0, 0);
  acc = MFMA_F16(a.h, b.l, acc, 0, 0, 0);
  acc = MFMA_F16(a.l, b.h, acc, 0, 0, 0);
  return acc;
}
} // namespace

__global__ __launch_bounds__(256) void ham_leapfrog(
    const float* __restrict__ mu, const float* __restrict__ Sigma,
    const float* __restrict__ phi, const float* __restrict__ pi_mu,
    const float* __restrict__ pi_Sigma, const float* __restrict__ pi_phi,
    const float* __restrict__ M_inv, float* __restrict__ out, int n_elem) {
  const int wave = threadIdx.x >> 6;
  const int lane = threadIdx.x & 63;
  const int e = blockIdx.x * (blockDim.x >> 6) + wave;
  if (e >= n_elem) return;

  const int c = lane & 15;
  const int r0 = (lane >> 4) * 4;
  const size_t eb = (size_t)e * 256;

  // ---- load Sigma, pi_Sigma, M_inv in C-layout (4 rows per lane at col c) ----
  f32x4 Sg, Pi, Mi;
#pragma unroll
  for (int j = 0; j < 4; ++j) {
    Sg[j] = Sigma[eb + (size_t)(r0 + j) * 16 + c];
    Pi[j] = pi_Sigma[eb + (size_t)(r0 + j) * 16 + c];
    Mi[j] = M_inv[eb + (size_t)(r0 + j) * 16 + c];
  }

  // ---- mu update: M_inv and pi_mu are loop-constant -> mu += 4*dt*(M_inv@pi_mu) ----
  const float pmc = pi_mu[(size_t)e * 16 + c];
  f32x4 am;
#pragma unroll
  for (int j = 0; j < 4; ++j) am[j] = Mi[j] * pmc;
#pragma unroll
  for (int m = 1; m < 16; m <<= 1) {
#pragma unroll
    for (int j = 0; j < 4; ++j) am[j] += __shfl_xor(am[j], m);
  }
  // every lane of each 16-lane group now holds row-sums for rows r0..r0+3

  // ---- phi update (3-vector, computed redundantly on all lanes) ----
  float p0 = phi[(size_t)e * 3 + 0];
  float p1 = phi[(size_t)e * 3 + 1];
  float p2 = phi[(size_t)e * 3 + 2];
  const float q0 = DT * pi_phi[(size_t)e * 3 + 0];
  const float q1 = DT * pi_phi[(size_t)e * 3 + 1];
  const float q2 = DT * pi_phi[(size_t)e * 3 + 2];
  const float TWO_PI = 6.28318530717958647692f;
  const float PI_F   = 3.14159265358979323846f;
  const float R_MAX  = 3.13159265358979323846f;  // pi - 0.01
#pragma unroll
  for (int s = 0; s < NSTEPS; ++s) {
    p0 += q0; p1 += q1; p2 += q2;
    float th  = sqrtf(p0 * p0 + p1 * p1 + p2 * p2);
    float inv = 1.0f / fmaxf(th, 1e-12f);
    float tw  = fmodf(th, TWO_PI);          // th >= 0, matches jnp.remainder
    bool  flip = tw > PI_F;
    float tf  = flip ? (TWO_PI - tw) : tw;
    float sgn = flip ? -1.f : 1.f;
    tf = fminf(tf, R_MAX);
    float f = sgn * inv * tf;
    p0 *= f; p1 *= f; p2 *= f;
  }

  // ---- leapfrog on (Sigma, pi_Sigma) ----
  Split sS = mksplit(Sg);
  Split sP = mksplit(Pi);

  for (int step = 0; step < NSTEPS; ++step) {
    // half kick: pi -= dt * pi*(Sigma*pi)   (== 0.5*dt * sym(2*(pi Sg) pi))
    {
      f32x4 V1 = mm(sS, sP);            // Sigma * pi   (left sym)
      f32x4 V2 = mm(sP, mksplit(V1));   // pi * V1      (left sym)
#pragma unroll
      for (int j = 0; j < 4; ++j) Pi[j] -= DT * V2[j];
      sP = mksplit(Pi);
    }
    // drift: Sigma <- S*exp(D*S), D = 2dt*pi, via Ytil_k = S*((D*Ytil_{k-1})/k)
    {
      f32x4 ACC = Sg;
      Split sY = sS;  // Ytil_0 = S (valid as B operand)
#pragma unroll
      for (int k = 1; k <= TM; ++k) {
        f32x4 U = mm(sP, sY);           // pi * Ytil    (left sym)
        const float sc = 2.0f * DT / (float)k;
#pragma unroll
        for (int j = 0; j < 4; ++j) U[j] *= sc;
        f32x4 Y = mm(sS, mksplit(U));   // S * U        (left sym)
#pragma unroll
        for (int j = 0; j < 4; ++j) ACC[j] += Y[j];
        sY = mksplit(Y);
      }
      Sg = ACC;
      sS = mksplit(Sg);
    }
    // second half kick (with updated Sigma)
    {
      f32x4 V1 = mm(sS, sP);
      f32x4 V2 = mm(sP, mksplit(V1));
#pragma unroll
      for (int j = 0; j < 4; ++j) Pi[j] -= DT * V2[j];
      sP = mksplit(Pi);
    }
  }

  // ---- stores: out = [mu | Sigma | phi] flat ----
  float* out_mu = out;
  float* out_Sg = out + (size_t)n_elem * 16;
  float* out_ph = out + (size_t)n_elem * (16 + 256);

#pragma unroll
  for (int j = 0; j < 4; ++j)
    out_Sg[eb + (size_t)(r0 + j) * 16 + c] = Sg[j];

  if (c == 0) {
#pragma unroll
    for (int j = 0; j < 4; ++j)
      out_mu[(size_t)e * 16 + r0 + j] =
          mu[(size_t)e * 16 + r0 + j] + ((float)NSTEPS * DT) * am[j];
  }
  if (lane == 0) {
    out_ph[(size_t)e * 3 + 0] = p0;
    out_ph[(size_t)e * 3 + 1] = p1;
    out_ph[(size_t)e * 3 + 2] = p2;
  }
}

extern "C" void kernel_launch(void* const* d_in, const int* in_sizes, int n_in,
                              void* d_out, int out_size, void* d_ws, size_t ws_size,
                              hipStream_t stream) {
  const float* mu       = (const float*)d_in[0];
  const float* Sigma    = (const float*)d_in[1];
  const float* phi      = (const float*)d_in[2];
  const float* pi_mu    = (const float*)d_in[3];
  const float* pi_Sigma = (const float*)d_in[4];
  const float* pi_phi   = (const float*)d_in[5];
  const float* M_inv    = (const float*)d_in[6];
  float* o = (float*)d_out;

  const int n_elem = in_sizes[0] / 16;          // B*N = 32768
  const int waves_per_block = 4;                // 256 threads
  const int blocks = (n_elem + waves_per_block - 1) / waves_per_block;
  hipLaunchKernelGGL(ham_leapfrog, dim3(blocks), dim3(256), 0, stream,
                     mu, Sigma, phi, pi_mu, pi_Sigma, pi_phi, M_inv, o, n_elem);
}

// Round 2
// 184.766 us; speedup vs baseline: 1.3497x; 1.3497x over previous
//
#include <hip/hip_runtime.h>
#include <math.h>

typedef float f32x4 __attribute__((ext_vector_type(4)));
typedef _Float16 f16x4 __attribute__((ext_vector_type(4)));

#define MFMA_F16 __builtin_amdgcn_mfma_f32_16x16x16f16

namespace {
constexpr float DT = 0.05f;
constexpr int NSTEPS = 4;

struct Split { f16x4 h; f16x4 l; };

// h-only split: 4 cvt + 2 pack
__device__ __forceinline__ f16x4 mkh(f32x4 v) {
  f16x4 h;
#pragma unroll
  for (int i = 0; i < 4; ++i) h[i] = (_Float16)v[i];
  return h;
}

// full hi/lo split; lo written as fma(-1,hi,x)->f16 to invite v_fma_mixlo_f16
__device__ __forceinline__ Split mksplit(f32x4 v) {
  Split s;
#pragma unroll
  for (int i = 0; i < 4; ++i) s.h[i] = (_Float16)v[i];
#pragma unroll
  for (int i = 0; i < 4; ++i)
    s.l[i] = (_Float16)fmaf(-1.0f, (float)s.h[i], v[i]);
  return s;
}

// Layout invariant (verified R1): matrices live in the 16x16 MFMA C/D layout
// (lane holds rows 4*(lane>>4)+i at col lane&15), which equals the B-fragment
// layout always and the A-fragment layout for symmetric matrices.
// mm*(a,b) = a*b, a MUST be symmetric; b arbitrary.
__device__ __forceinline__ f32x4 mm3(Split a, Split b) {
  f32x4 acc = {0.f, 0.f, 0.f, 0.f};
  acc = MFMA_F16(a.h, b.h, acc, 0, 0, 0);
  acc = MFMA_F16(a.h, b.l, acc, 0, 0, 0);
  acc = MFMA_F16(a.l, b.h, acc, 0, 0, 0);
  return acc;
}
__device__ __forceinline__ f32x4 mm2(Split a, f16x4 bh) {
  f32x4 acc = {0.f, 0.f, 0.f, 0.f};
  acc = MFMA_F16(a.h, bh, acc, 0, 0, 0);
  acc = MFMA_F16(a.l, bh, acc, 0, 0, 0);
  return acc;
}
__device__ __forceinline__ f32x4 mm1(f16x4 ah, f16x4 bh) {
  f32x4 acc = {0.f, 0.f, 0.f, 0.f};
  acc = MFMA_F16(ah, bh, acc, 0, 0, 0);
  return acc;
}
} // namespace

__global__ __launch_bounds__(256) void ham_leapfrog(
    const float* __restrict__ mu, const float* __restrict__ Sigma,
    const float* __restrict__ phi, const float* __restrict__ pi_mu,
    const float* __restrict__ pi_Sigma, const float* __restrict__ pi_phi,
    const float* __restrict__ M_inv, float* __restrict__ out, int n_elem) {
  const int wave = threadIdx.x >> 6;
  const int lane = threadIdx.x & 63;
  const int e = blockIdx.x * (blockDim.x >> 6) + wave;
  if (e >= n_elem) return;

  const int c = lane & 15;
  const int r0 = (lane >> 4) * 4;
  const size_t eb = (size_t)e * 256;

  // ---- load Sigma, pi_Sigma (-> D = 2dt*pi), M_inv in C-layout ----
  f32x4 Sg, Dv, Mi;
#pragma unroll
  for (int j = 0; j < 4; ++j) {
    Sg[j] = Sigma[eb + (size_t)(r0 + j) * 16 + c];
    Dv[j] = pi_Sigma[eb + (size_t)(r0 + j) * 16 + c];
    Mi[j] = M_inv[eb + (size_t)(r0 + j) * 16 + c];
  }
  Dv = (2.0f * DT) * Dv;  // D = 2*dt*pi; kick: D -= 0.5*D*Sigma*D; drift uses D

  // ---- mu: M_inv, pi_mu loop-constant -> mu += 4*dt*(M_inv@pi_mu) ----
  const float pmc = pi_mu[(size_t)e * 16 + c];
  f32x4 am = Mi * pmc;
#pragma unroll
  for (int m = 1; m < 16; m <<= 1) {
#pragma unroll
    for (int j = 0; j < 4; ++j) am[j] += __shfl_xor(am[j], m);
  }

  // ---- phi update (redundant on all lanes) ----
  float p0 = phi[(size_t)e * 3 + 0];
  float p1 = phi[(size_t)e * 3 + 1];
  float p2 = phi[(size_t)e * 3 + 2];
  const float q0 = DT * pi_phi[(size_t)e * 3 + 0];
  const float q1 = DT * pi_phi[(size_t)e * 3 + 1];
  const float q2 = DT * pi_phi[(size_t)e * 3 + 2];
  const float TWO_PI = 6.28318530717958647692f;
  const float INV_2PI = 0.15915494309189533577f;
  const float PI_F = 3.14159265358979323846f;
  const float R_MAX = 3.13159265358979323846f;  // pi - 0.01
#pragma unroll
  for (int s = 0; s < NSTEPS; ++s) {
    p0 += q0; p1 += q1; p2 += q2;
    float th = sqrtf(p0 * p0 + p1 * p1 + p2 * p2);
    float inv = 1.0f / fmaxf(th, 1e-12f);
    float tw = th - TWO_PI * floorf(th * INV_2PI);  // remainder, th >= 0
    bool flip = tw > PI_F;
    float tf = flip ? (TWO_PI - tw) : tw;
    float sgn = flip ? -1.f : 1.f;
    tf = fminf(tf, R_MAX);
    float f = sgn * inv * tf;
    p0 *= f; p1 *= f; p2 *= f;
  }

  // ---- leapfrog on (Sigma, D) ----
  Split sS = mksplit(Sg);
  Split sD = mksplit(Dv);

  for (int step = 0; step < NSTEPS; ++step) {
    // half kick: D -= 0.5 * D*(Sigma*D)
    {
      f32x4 T = mm3(sS, sD);      // Sigma*D   (left sym; T as B-operand ok)
      Split sT = mksplit(T);
      f32x4 K = mm3(sD, sT);      // D*T       (left sym)
      Dv = Dv - 0.5f * K;
      sD = mksplit(Dv);
    }
    // drift: Sigma <- S*exp(D*S) = Sg + sum_k (1/k!)*Y_k,  Y_k = S*(D*Y_{k-1}), Y_0 = S
    {
      f32x4 ACC = Sg;
      // k = 1: full precision
      f32x4 U = mm3(sD, sS);
      Split sU = mksplit(U);
      f32x4 Y = mm3(sS, sU);
      ACC += Y;
      f16x4 yh = mkh(Y);
      // k = 2: 2-term (drop B.lo; term ~0.2, err ~1e-3)
      U = mm2(sD, yh);
      f16x4 uh = mkh(U);
      Y = mm2(sS, uh);
      ACC += 0.5f * Y;
      yh = mkh(Y);
      // k = 3..5: pure h*h (terms <~0.02, err ~3e-5)
      U = mm1(sD.h, yh); uh = mkh(U);
      Y = mm1(sS.h, uh); ACC += (1.0f / 6.0f) * Y; yh = mkh(Y);
      U = mm1(sD.h, yh); uh = mkh(U);
      Y = mm1(sS.h, uh); ACC += (1.0f / 24.0f) * Y; yh = mkh(Y);
      U = mm1(sD.h, yh); uh = mkh(U);
      Y = mm1(sS.h, uh); ACC += (1.0f / 120.0f) * Y;
      Sg = ACC;
      sS = mksplit(Sg);
    }
    // second half kick (updated Sigma)
    {
      f32x4 T = mm3(sS, sD);
      Split sT = mksplit(T);
      f32x4 K = mm3(sD, sT);
      Dv = Dv - 0.5f * K;
      sD = mksplit(Dv);
    }
  }

  // ---- stores: out = [mu | Sigma | phi] flat ----
  float* out_mu = out;
  float* out_Sg = out + (size_t)n_elem * 16;
  float* out_ph = out + (size_t)n_elem * (16 + 256);

#pragma unroll
  for (int j = 0; j < 4; ++j)
    out_Sg[eb + (size_t)(r0 + j) * 16 + c] = Sg[j];

  if (c == 0) {
#pragma unroll
    for (int j = 0; j < 4; ++j)
      out_mu[(size_t)e * 16 + r0 + j] =
          mu[(size_t)e * 16 + r0 + j] + ((float)NSTEPS * DT) * am[j];
  }
  if (lane == 0) {
    out_ph[(size_t)e * 3 + 0] = p0;
    out_ph[(size_t)e * 3 + 1] = p1;
    out_ph[(size_t)e * 3 + 2] = p2;
  }
}

extern "C" void kernel_launch(void* const* d_in, const int* in_sizes, int n_in,
                              void* d_out, int out_size, void* d_ws, size_t ws_size,
                              hipStream_t stream) {
  const float* mu       = (const float*)d_in[0];
  const float* Sigma    = (const float*)d_in[1];
  const float* phi      = (const float*)d_in[2];
  const float* pi_mu    = (const float*)d_in[3];
  const float* pi_Sigma = (const float*)d_in[4];
  const float* pi_phi   = (const float*)d_in[5];
  const float* M_inv    = (const float*)d_in[6];
  float* o = (float*)d_out;

  const int n_elem = in_sizes[0] / 16;          // B*N = 32768
  const int waves_per_block = 4;                // 256 threads
  const int blocks = (n_elem + waves_per_block - 1) / waves_per_block;
  hipLaunchKernelGGL(ham_leapfrog, dim3(blocks), dim3(256), 0, stream,
                     mu, Sigma, phi, pi_mu, pi_Sigma, pi_phi, M_inv, o, n_elem);
}

// Round 4
// 163.596 us; speedup vs baseline: 1.5243x; 1.1294x over previous
//
#include <hip/hip_runtime.h>
#include <math.h>

typedef float f32x4 __attribute__((ext_vector_type(4)));
typedef _Float16 f16x4 __attribute__((ext_vector_type(4)));
typedef __fp16 fp16x2 __attribute__((ext_vector_type(2)));
typedef __fp16 fp16x4 __attribute__((ext_vector_type(4)));

#define MFMA_F16 __builtin_amdgcn_mfma_f32_16x16x16f16

namespace {
constexpr float DT = 0.05f;
constexpr int NSTEPS = 4;

struct Split { f16x4 h; f16x4 l; };

// 4x f32 -> packed f16x4 via v_cvt_pkrtz_f16_f32 (2 instrs)
__device__ __forceinline__ f16x4 pk4(f32x4 v) {
  fp16x2 a = __builtin_amdgcn_cvt_pkrtz(v[0], v[1]);
  fp16x2 b = __builtin_amdgcn_cvt_pkrtz(v[2], v[3]);
  fp16x4 r = __builtin_shufflevector(a, b, 0, 1, 2, 3);
  return __builtin_bit_cast(f16x4, r);
}

// full hi/lo split: hi = RTZ(x); lo = RTZ(x - hi). ~12 instrs.
__device__ __forceinline__ Split mksplit(f32x4 v) {
  Split s;
  s.h = pk4(v);
  f32x4 hf;
#pragma unroll
  for (int i = 0; i < 4; ++i) hf[i] = (float)s.h[i];
  s.l = pk4(v - hf);
  return s;
}

// Layout invariant: all matrices live in the 16x16 MFMA C/D layout
// (lane holds rows 4*(lane>>4)+i at col lane&15). This equals the B-fragment
// layout always; feeding a matrix M's C-layout regs as the A-operand computes
// with M^T, so the left operand must be symmetric.
// mm*(a,b) = a*b, a MUST be symmetric; b arbitrary.
__device__ __forceinline__ f32x4 mm3(Split a, Split b) {
  f32x4 acc = {0.f, 0.f, 0.f, 0.f};
  acc = MFMA_F16(a.h, b.h, acc, 0, 0, 0);
  acc = MFMA_F16(a.h, b.l, acc, 0, 0, 0);
  acc = MFMA_F16(a.l, b.h, acc, 0, 0, 0);
  return acc;
}
__device__ __forceinline__ f32x4 mm2(Split a, f16x4 bh) {
  f32x4 acc = {0.f, 0.f, 0.f, 0.f};
  acc = MFMA_F16(a.h, bh, acc, 0, 0, 0);
  acc = MFMA_F16(a.l, bh, acc, 0, 0, 0);
  return acc;
}
__device__ __forceinline__ f32x4 mm1(f16x4 ah, f16x4 bh) {
  f32x4 acc = {0.f, 0.f, 0.f, 0.f};
  acc = MFMA_F16(ah, bh, acc, 0, 0, 0);
  return acc;
}
} // namespace

__global__ __launch_bounds__(256) void ham_leapfrog(
    const float* __restrict__ mu, const float* __restrict__ Sigma,
    const float* __restrict__ phi, const float* __restrict__ pi_mu,
    const float* __restrict__ pi_Sigma, const float* __restrict__ pi_phi,
    const float* __restrict__ M_inv, float* __restrict__ out, int n_elem) {
  const int wave = threadIdx.x >> 6;
  const int lane = threadIdx.x & 63;
  const int e = blockIdx.x * (blockDim.x >> 6) + wave;
  if (e >= n_elem) return;

  const int c = lane & 15;
  const int r0 = (lane >> 4) * 4;
  const int eb = e * 256;          // fits int: 32768*256 = 8.4M
  const int ev = e * 16;

  // ---- load Sigma, pi_Sigma (-> D = 2dt*pi), M_inv in C-layout ----
  f32x4 Sg, Dv, Mi;
#pragma unroll
  for (int j = 0; j < 4; ++j) {
    const int off = eb + (r0 + j) * 16 + c;
    Sg[j] = Sigma[off];
    Dv[j] = pi_Sigma[off];
    Mi[j] = M_inv[off];
  }
  Dv = (2.0f * DT) * Dv;  // D = 2*dt*pi

  // ---- mu via MFMA: am = M_inv @ P, P has pi_mu in column 0 ----
  // B-fragment: lanes with c==0 hold rows r0..r0+3 of column 0.
  f32x4 pm4 = *(const f32x4*)(pi_mu + ev + r0);
  f16x4 Ph = pk4(pm4);
  if (c != 0) Ph = (f16x4)(_Float16)0;
  f32x4 am = mm1(pk4(Mi), Ph);  // column 0 (at lanes c==0) = M_inv @ pi_mu

  // ---- phi update (redundant on all lanes) ----
  float p0 = phi[e * 3 + 0];
  float p1 = phi[e * 3 + 1];
  float p2 = phi[e * 3 + 2];
  const float q0 = DT * pi_phi[e * 3 + 0];
  const float q1 = DT * pi_phi[e * 3 + 1];
  const float q2 = DT * pi_phi[e * 3 + 2];
  const float TWO_PI = 6.28318530717958647692f;
  const float INV_2PI = 0.15915494309189533577f;
  const float PI_F = 3.14159265358979323846f;
  const float R_MAX = 3.13159265358979323846f;  // pi - 0.01
#pragma unroll
  for (int s = 0; s < NSTEPS; ++s) {
    p0 += q0; p1 += q1; p2 += q2;
    float th = sqrtf(p0 * p0 + p1 * p1 + p2 * p2);
    float inv = __builtin_amdgcn_rcpf(fmaxf(th, 1e-12f));
    float tw = th - TWO_PI * floorf(th * INV_2PI);  // remainder, th >= 0
    bool flip = tw > PI_F;
    float tf = flip ? (TWO_PI - tw) : tw;
    float sgn = flip ? -1.f : 1.f;
    tf = fminf(tf, R_MAX);
    float f = sgn * inv * tf;
    p0 *= f; p1 *= f; p2 *= f;
  }

  // ---- leapfrog on (Sigma, D) ----
  Split sS = mksplit(Sg);
  Split sD = mksplit(Dv);

#pragma unroll
  for (int step = 0; step < NSTEPS; ++step) {
    // half kick: D -= 0.5 * D*(Sigma*D)
    {
      f32x4 T = mm3(sS, sD);        // S*D, full precision (D.lo matters here)
      f32x4 K = mm2(sD, pk4(T));    // D*T, dropping T.lo: err ~5e-6
      Dv = Dv - 0.5f * K;
      sD = mksplit(Dv);
    }
    // drift: Sigma <- S*exp(D*S) = sum_k Z_k/k!, Z_k = S(DS)^k = Z_{k-1}*X, X = D*S
    {
      f32x4 X = mm3(sD, sS);        // X = D*S (C-layout; used only as B-operand)
      Split sX = mksplit(X);
      f32x4 Z = mm3(sS, sX);        // Z1 = S*X
      f32x4 ACC = Sg + Z;
      f16x4 zh = pk4(Z);
      Z = mm1(zh, sX.h); ACC += (1.0f / 2.0f) * Z; zh = pk4(Z);   // Z2 = Z1*X
      Z = mm1(zh, sX.h); ACC += (1.0f / 6.0f) * Z; zh = pk4(Z);   // Z3
      Z = mm1(zh, sX.h); ACC += (1.0f / 24.0f) * Z; zh = pk4(Z);  // Z4
      Z = mm1(zh, sX.h); ACC += (1.0f / 120.0f) * Z;              // Z5
      Sg = ACC;
      sS = mksplit(Sg);
    }
    // second half kick (updated Sigma)
    {
      f32x4 T = mm3(sS, sD);
      f32x4 K = mm2(sD, pk4(T));
      Dv = Dv - 0.5f * K;
      sD = mksplit(Dv);
    }
  }

  // ---- stores: out = [mu | Sigma | phi] flat ----
  float* out_mu = out;
  float* out_Sg = out + (size_t)n_elem * 16;
  float* out_ph = out + (size_t)n_elem * (16 + 256);

#pragma unroll
  for (int j = 0; j < 4; ++j)
    out_Sg[eb + (r0 + j) * 16 + c] = Sg[j];

  if (c == 0) {
    f32x4 mu4 = *(const f32x4*)(mu + ev + r0);
    *(f32x4*)(out_mu + ev + r0) = mu4 + ((float)NSTEPS * DT) * am;
  }
  if (lane == 0) {
    out_ph[e * 3 + 0] = p0;
    out_ph[e * 3 + 1] = p1;
    out_ph[e * 3 + 2] = p2;
  }
}

extern "C" void kernel_launch(void* const* d_in, const int* in_sizes, int n_in,
                              void* d_out, int out_size, void* d_ws, size_t ws_size,
                              hipStream_t stream) {
  const float* mu       = (const float*)d_in[0];
  const float* Sigma    = (const float*)d_in[1];
  const float* phi      = (const float*)d_in[2];
  const float* pi_mu    = (const float*)d_in[3];
  const float* pi_Sigma = (const float*)d_in[4];
  const float* pi_phi   = (const float*)d_in[5];
  const float* M_inv    = (const float*)d_in[6];
  float* o = (float*)d_out;

  const int n_elem = in_sizes[0] / 16;          // B*N = 32768
  const int waves_per_block = 4;                // 256 threads
  const int blocks = (n_elem + waves_per_block - 1) / waves_per_block;
  hipLaunchKernelGGL(ham_leapfrog, dim3(blocks), dim3(256), 0, stream,
                     mu, Sigma, phi, pi_mu, pi_Sigma, pi_phi, M_inv, o, n_elem);
}

// Round 5
// 153.073 us; speedup vs baseline: 1.6291x; 1.0687x over previous
//
#include <hip/hip_runtime.h>
#include <math.h>

typedef float f32x4 __attribute__((ext_vector_type(4)));
typedef _Float16 f16x4 __attribute__((ext_vector_type(4)));
typedef __fp16 fp16x2 __attribute__((ext_vector_type(2)));
typedef __fp16 fp16x4 __attribute__((ext_vector_type(4)));

#define MFMA_F16 __builtin_amdgcn_mfma_f32_16x16x16f16

namespace {
constexpr float DT = 0.05f;
constexpr int NSTEPS = 4;

struct Split { f16x4 h; f16x4 l; };

// 4x f32 -> packed f16x4 via v_cvt_pkrtz_f16_f32 (2 instrs)
__device__ __forceinline__ f16x4 pk4(f32x4 v) {
  fp16x2 a = __builtin_amdgcn_cvt_pkrtz(v[0], v[1]);
  fp16x2 b = __builtin_amdgcn_cvt_pkrtz(v[2], v[3]);
  fp16x4 r = __builtin_shufflevector(a, b, 0, 1, 2, 3);
  return __builtin_bit_cast(f16x4, r);
}

// full hi/lo split: hi = RTZ(x); lo = RTZ(x - hi). ~12 instrs.
__device__ __forceinline__ Split mksplit(f32x4 v) {
  Split s;
  s.h = pk4(v);
  f32x4 hf;
#pragma unroll
  for (int i = 0; i < 4; ++i) hf[i] = (float)s.h[i];
  s.l = pk4(v - hf);
  return s;
}

// Layout invariant: all matrices live in the 16x16 MFMA C/D layout
// (lane holds rows 4*(lane>>4)+i at col lane&15). This equals the B-fragment
// layout always; feeding a matrix M's C-layout regs as the A-operand computes
// with M^T, so the left operand must be symmetric.
// mm*(a,b) = a*b, a MUST be symmetric; b arbitrary.
__device__ __forceinline__ f32x4 mm3(Split a, Split b) {
  f32x4 acc = {0.f, 0.f, 0.f, 0.f};
  acc = MFMA_F16(a.h, b.h, acc, 0, 0, 0);
  acc = MFMA_F16(a.h, b.l, acc, 0, 0, 0);
  acc = MFMA_F16(a.l, b.h, acc, 0, 0, 0);
  return acc;
}
// acc0 + a*b  (2-term; b is h-only)
__device__ __forceinline__ f32x4 mm2_acc(Split a, f16x4 bh, f32x4 acc0) {
  f32x4 acc = acc0;
  acc = MFMA_F16(a.h, bh, acc, 0, 0, 0);
  acc = MFMA_F16(a.l, bh, acc, 0, 0, 0);
  return acc;
}
__device__ __forceinline__ f32x4 mm1(f16x4 ah, f16x4 bh) {
  f32x4 acc = {0.f, 0.f, 0.f, 0.f};
  acc = MFMA_F16(ah, bh, acc, 0, 0, 0);
  return acc;
}
} // namespace

// min 4 waves/EU -> <=128 VGPR budget: keep state in arch VGPRs, avoid
// v_accvgpr shuttling (R4: VGPR_Count=28 + VALU 3x source estimate).
__global__ __launch_bounds__(256, 4) void ham_leapfrog(
    const float* __restrict__ mu, const float* __restrict__ Sigma,
    const float* __restrict__ phi, const float* __restrict__ pi_mu,
    const float* __restrict__ pi_Sigma, const float* __restrict__ pi_phi,
    const float* __restrict__ M_inv, float* __restrict__ out, int n_elem) {
  const int wave = threadIdx.x >> 6;
  const int lane = threadIdx.x & 63;
  const int e = blockIdx.x * (blockDim.x >> 6) + wave;
  if (e >= n_elem) return;

  const int c = lane & 15;
  const int r0 = (lane >> 4) * 4;
  const int eb = e * 256;          // fits int: 32768*256 = 8.4M
  const int ev = e * 16;

  // ---- load Sigma, pi_Sigma (-> D = 2dt*pi), M_inv in C-layout ----
  f32x4 Sg, Dv, Mi;
#pragma unroll
  for (int j = 0; j < 4; ++j) {
    const int off = eb + (r0 + j) * 16 + c;
    Sg[j] = Sigma[off];
    Dv[j] = pi_Sigma[off];
    Mi[j] = M_inv[off];
  }
  Dv = (2.0f * DT) * Dv;  // D = 2*dt*pi

  // ---- mu via MFMA: am = M_inv @ P, P has pi_mu in column 0 ----
  f32x4 pm4 = *(const f32x4*)(pi_mu + ev + r0);
  f16x4 Ph = pk4(pm4);
  if (c != 0) Ph = (f16x4)(_Float16)0;
  f32x4 am = mm1(pk4(Mi), Ph);  // column 0 (lanes c==0) = M_inv @ pi_mu

  // ---- phi update (redundant on all lanes) ----
  float p0 = phi[e * 3 + 0];
  float p1 = phi[e * 3 + 1];
  float p2 = phi[e * 3 + 2];
  const float q0 = DT * pi_phi[e * 3 + 0];
  const float q1 = DT * pi_phi[e * 3 + 1];
  const float q2 = DT * pi_phi[e * 3 + 2];
  const float TWO_PI = 6.28318530717958647692f;
  const float INV_2PI = 0.15915494309189533577f;
  const float PI_F = 3.14159265358979323846f;
  const float R_MAX = 3.13159265358979323846f;  // pi - 0.01
#pragma unroll
  for (int s = 0; s < NSTEPS; ++s) {
    p0 += q0; p1 += q1; p2 += q2;
    float th = sqrtf(p0 * p0 + p1 * p1 + p2 * p2);
    float inv = __builtin_amdgcn_rcpf(fmaxf(th, 1e-12f));
    float tw = th - TWO_PI * floorf(th * INV_2PI);  // remainder, th >= 0
    bool flip = tw > PI_F;
    float tf = flip ? (TWO_PI - tw) : tw;
    float sgn = flip ? -1.f : 1.f;
    tf = fminf(tf, R_MAX);
    float f = sgn * inv * tf;
    p0 *= f; p1 *= f; p2 *= f;
  }

  // ---- leapfrog on (Sigma, D) ----
  Split sS = mksplit(Sg);
  Split sD = mksplit(Dv);

#pragma unroll
  for (int step = 0; step < NSTEPS; ++step) {
    // half kick: D += D*(-0.5*S*D), acc-initialized with D
    {
      f32x4 T = mm3(sS, sD);           // S*D, full precision
      f16x4 Th = pk4(-0.5f * T);       // fold -0.5 into B-operand
      Dv = mm2_acc(sD, Th, Dv);        // Dv - 0.5*D*T
      sD = mksplit(Dv);
    }
    // drift: Sigma <- S*exp(D*S) = sum_k Z_k/k!, Z_k = Z_{k-1}*X, X = D*S
    {
      f32x4 X = mm3(sD, sS);           // X = D*S (used only as B-operand)
      Split sX = mksplit(X);
      f32x4 Z = mm3(sS, sX);           // Z1 = S*X
      f32x4 ACC = Sg + Z;
      f16x4 zh = pk4(Z);
      Z = mm1(zh, sX.h); ACC += (1.0f / 2.0f) * Z; zh = pk4(Z);   // Z2
      Z = mm1(zh, sX.h); ACC += (1.0f / 6.0f) * Z; zh = pk4(Z);   // Z3
      Z = mm1(zh, sX.h); ACC += (1.0f / 24.0f) * Z;               // Z4
      Sg = ACC;
      sS = mksplit(Sg);
    }
    // second half kick (updated Sigma)
    {
      f32x4 T = mm3(sS, sD);
      f16x4 Th = pk4(-0.5f * T);
      Dv = mm2_acc(sD, Th, Dv);
      sD = mksplit(Dv);
    }
  }

  // ---- stores: out = [mu | Sigma | phi] flat ----
  float* out_mu = out;
  float* out_Sg = out + (size_t)n_elem * 16;
  float* out_ph = out + (size_t)n_elem * (16 + 256);

#pragma unroll
  for (int j = 0; j < 4; ++j)
    out_Sg[eb + (r0 + j) * 16 + c] = Sg[j];

  if (c == 0) {
    f32x4 mu4 = *(const f32x4*)(mu + ev + r0);
    *(f32x4*)(out_mu + ev + r0) = mu4 + ((float)NSTEPS * DT) * am;
  }
  if (lane == 0) {
    out_ph[e * 3 + 0] = p0;
    out_ph[e * 3 + 1] = p1;
    out_ph[e * 3 + 2] = p2;
  }
}

extern "C" void kernel_launch(void* const* d_in, const int* in_sizes, int n_in,
                              void* d_out, int out_size, void* d_ws, size_t ws_size,
                              hipStream_t stream) {
  const float* mu       = (const float*)d_in[0];
  const float* Sigma    = (const float*)d_in[1];
  const float* phi      = (const float*)d_in[2];
  const float* pi_mu    = (const float*)d_in[3];
  const float* pi_Sigma = (const float*)d_in[4];
  const float* pi_phi   = (const float*)d_in[5];
  const float* M_inv    = (const float*)d_in[6];
  float* o = (float*)d_out;

  const int n_elem = in_sizes[0] / 16;          // B*N = 32768
  const int waves_per_block = 4;                // 256 threads
  const int blocks = (n_elem + waves_per_block - 1) / waves_per_block;
  hipLaunchKernelGGL(ham_leapfrog, dim3(blocks), dim3(256), 0, stream,
                     mu, Sigma, phi, pi_mu, pi_Sigma, pi_phi, M_inv, o, n_elem);
}